// Round 7
// baseline (826.097 us; speedup 1.0000x reference)
//
#include <hip/hip_runtime.h>
#include <math.h>

#define N_TOK 131072
#define K_CB  1024
#define D_DIM 64
#define MARGIN 0.0625f

// ws layout: en[1024] f32 @0 ; esplit[1024*128] bf16 @4096 ; fixcnt @266240 ; fixlist @266248
#define WS_EN     0
#define WS_ES     4096
#define WS_CNT    266240
#define WS_LIST   266248

typedef short bf16x8 __attribute__((ext_vector_type(8)));
typedef float f32x4  __attribute__((ext_vector_type(4)));

__device__ __forceinline__ ushort f2bf(float f) {   // RNE fp32->bf16
    uint u = __float_as_uint(f);
    u += 0x7FFFu + ((u >> 16) & 1u);
    return (ushort)(u >> 16);
}
__device__ __forceinline__ float bf2f(ushort h) {
    return __uint_as_float(((uint)h) << 16);
}

// ---- kernel 1: prep. 16 blocks x 64 codes; en[k] (R1-sequential rounding) + bf16 hi/lo split.
__global__ __launch_bounds__(256) void prep_kernel(
    const float* __restrict__ emb, float* __restrict__ en,
    ushort* __restrict__ es, uint* __restrict__ fixcnt)
{
    const int tid = threadIdx.x;
    const int pb  = blockIdx.x;
    const int c6  = tid & 63;
    const int q   = tid >> 6;
    const int code = pb * 64 + c6;
    if (pb == 0 && tid == 0) *fixcnt = 0;

    const float* er = emb + (size_t)code * D_DIM;
    #pragma unroll
    for (int j = 0; j < 16; ++j) {
        float f = er[q * 16 + j];
        ushort h = f2bf(f);
        es[(size_t)code * 128 + q * 16 + j]      = h;
        es[(size_t)code * 128 + 64 + q * 16 + j] = f2bf(f - bf2f(h));
    }
    if (q == 0) {
        float s = 0.f;
        #pragma unroll
        for (int d = 0; d < D_DIM; ++d) s = fmaf(er[d], er[d], s);
        en[code] = s;
    }
}

// ---- kernel 2: fully wave-independent. Each wave: 16 rows' split-bf16 MFMA argmin
// (hi*hi + hi*lo + lo*hi), shuffle-only top-2 merge, then streams its own 16 one-hot
// rows (full 1KB rows: zeros + the 1.0) + zq. No LDS, no __syncthreads, no pre-fill.
// block = 256 thr = 4 waves x 16 rows = 64 rows/block; grid 2048.
__global__ __launch_bounds__(256) void vq_onehot(
    const float* __restrict__ x, const float* __restrict__ emb,
    const float* __restrict__ en, const ushort* __restrict__ es,
    float* __restrict__ zq, float* __restrict__ probs,
    uint* __restrict__ fixcnt, uint* __restrict__ fixlist, uint fixcap)
{
    const int tid  = threadIdx.x;
    const int wave = tid >> 6, lane = tid & 63;
    const int quad = lane >> 4, l15 = lane & 15;
    const int waveRow = blockIdx.x * 64 + wave * 16;

    // A-frags for this wave's 16 rows: [0]=hi d0..31, [1]=hi d32..63, [2]=lo d0..31, [3]=lo d32..63.
    // A layout (m120): A[m=lane&15][k=quad*8+j].
    bf16x8 af[4];
    {
        const float* xr = x + (size_t)(waveRow + l15) * D_DIM + quad * 8;
        f32x4 p0 = *(const f32x4*)(xr);
        f32x4 p1 = *(const f32x4*)(xr + 4);
        f32x4 p2 = *(const f32x4*)(xr + 32);
        f32x4 p3 = *(const f32x4*)(xr + 36);
        float v0[8], v1[8];
        #pragma unroll
        for (int j = 0; j < 4; ++j) { v0[j] = p0[j]; v0[4 + j] = p1[j]; v1[j] = p2[j]; v1[4 + j] = p3[j]; }
        #pragma unroll
        for (int j = 0; j < 8; ++j) {
            ushort h0 = f2bf(v0[j]);
            af[0][j] = (short)h0;
            af[2][j] = (short)f2bf(v0[j] - bf2f(h0));
            ushort h1 = f2bf(v1[j]);
            af[1][j] = (short)h1;
            af[3][j] = (short)f2bf(v1[j] - bf2f(h1));
        }
    }

    float b1[4], b2[4]; int k1[4];
    #pragma unroll
    for (int r = 0; r < 4; ++r) { b1[r] = INFINITY; b2[r] = INFINITY; k1[r] = 0; }

    const bf16x8* __restrict__ esv = (const bf16x8*)es;  // 16 frags per code row

    for (int cb = 0; cb < 64; ++cb) {
        const int code = cb * 16 + l15;
        // B-frags: B[k=quad*8+j][n=lane&15]; [0]=hi d0..31, [1]=hi d32..63, [2]=lo, [3]=lo
        bf16x8 bfr[4];
        #pragma unroll
        for (int ks = 0; ks < 4; ++ks) bfr[ks] = esv[(size_t)code * 16 + ks * 4 + quad];

        f32x4 acc = {0.f, 0.f, 0.f, 0.f};
        // dot = xh*eh + xh*el + xl*eh  (xl*el ~1e-4, absorbed by MARGIN)
        acc = __builtin_amdgcn_mfma_f32_16x16x32_bf16(af[0], bfr[0], acc, 0, 0, 0);
        acc = __builtin_amdgcn_mfma_f32_16x16x32_bf16(af[1], bfr[1], acc, 0, 0, 0);
        acc = __builtin_amdgcn_mfma_f32_16x16x32_bf16(af[0], bfr[2], acc, 0, 0, 0);
        acc = __builtin_amdgcn_mfma_f32_16x16x32_bf16(af[1], bfr[3], acc, 0, 0, 0);
        acc = __builtin_amdgcn_mfma_f32_16x16x32_bf16(af[2], bfr[0], acc, 0, 0, 0);
        acc = __builtin_amdgcn_mfma_f32_16x16x32_bf16(af[3], bfr[1], acc, 0, 0, 0);

        const float env = en[code];   // 64B segment per wave, L1/L2-hot
        // C layout (m89): col = lane&15 (this lane's code), row = quad*4 + r.
        #pragma unroll
        for (int r = 0; r < 4; ++r) {
            float d = fmaf(-2.f, acc[r], env);
            bool lt = d < b1[r];
            b2[r] = lt ? b1[r] : fminf(b2[r], d);
            k1[r] = lt ? code : k1[r];
            b1[r] = lt ? d : b1[r];
        }
    }

    // butterfly top-2 merge across the 16 lanes of each quad (all lanes get result)
    #pragma unroll
    for (int r = 0; r < 4; ++r) {
        #pragma unroll
        for (int off = 1; off < 16; off <<= 1) {
            float ob1 = __shfl_xor(b1[r], off);
            int   ok1 = __shfl_xor(k1[r], off);
            float ob2 = __shfl_xor(b2[r], off);
            bool better = (ob1 < b1[r]) || (ob1 == b1[r] && ok1 < k1[r]);
            float loser = better ? b1[r] : ob1;
            b1[r] = better ? ob1 : b1[r];
            k1[r] = better ? ok1 : k1[r];
            b2[r] = fminf(fminf(b2[r], ob2), loser);
        }
    }

    // per-row emit, fully unrolled (row m lives in quad m>>2, slot m&3)
    #pragma unroll
    for (int m = 0; m < 16; ++m) {
        const int src = (m >> 2) << 4;
        const int   bk  = __shfl(k1[m & 3], src);
        const float bb1 = __shfl(b1[m & 3], src);
        const float bb2 = __shfl(b2[m & 3], src);
        const int grow = waveRow + m;

        // one-hot row: 4 x 16B per lane, each step a contiguous 1KB wave-store
        float* prow = probs + (size_t)grow * K_CB;
        #pragma unroll
        for (int s = 0; s < 4; ++s) {
            int c = s * 256 + lane * 4;
            f32x4 v;
            v[0] = (c     == bk) ? 1.f : 0.f;
            v[1] = (c + 1 == bk) ? 1.f : 0.f;
            v[2] = (c + 2 == bk) ? 1.f : 0.f;
            v[3] = (c + 3 == bk) ? 1.f : 0.f;
            __builtin_nontemporal_store(v, (f32x4*)(prow + c));
        }
        // zq row: 16 lanes x 16B gather from L2-hot emb (exact fp32 copy)
        if (lane < 16)
            ((f32x4*)(zq + (size_t)grow * D_DIM))[lane] =
                ((const f32x4*)(emb + (size_t)bk * D_DIM))[lane];
        // uncertain -> fixup list
        if (lane == 0 && bb2 - bb1 <= MARGIN) {
            uint idx = atomicAdd(fixcnt, 1u);
            if (idx < fixcap) fixlist[idx] = (uint)grow | ((uint)bk << 17);
        }
    }
}

// ---- kernel 3: exact fp32 re-argmin (bit-identical to the R1/R2 formula) for flagged rows ----
__global__ __launch_bounds__(256) void vq_fixup(
    const float* __restrict__ x, const float* __restrict__ emb,
    const float* __restrict__ en,
    float* __restrict__ zq, float* __restrict__ probs,
    const uint* __restrict__ fixcnt, const uint* __restrict__ fixlist, uint fixcap)
{
    const int lane = threadIdx.x & 63;
    const uint gwave = (uint)((blockIdx.x * 256 + threadIdx.x) >> 6);
    uint cnt = *fixcnt;
    if (cnt > fixcap) cnt = fixcap;

    for (uint e = gwave; e < cnt; e += 1024u) {
        uint w = fixlist[e];
        int row = (int)(w & 0x1FFFFu);
        int kg  = (int)(w >> 17);
        const float* xr = x + (size_t)row * D_DIM;
        float xn = 0.f;
        #pragma unroll
        for (int d = 0; d < D_DIM; ++d) xn = fmaf(xr[d], xr[d], xn);

        float bd = INFINITY; int bk = 0;
        for (int t = 0; t < 16; ++t) {
            int code = t * 64 + lane;                 // ascending per lane
            const float* er = emb + (size_t)code * D_DIM;
            float a0 = 0.f, a1 = 0.f, a2 = 0.f, a3 = 0.f;
            #pragma unroll
            for (int d = 0; d < D_DIM; d += 4) {
                a0 = fmaf(xr[d + 0], er[d + 0], a0);
                a1 = fmaf(xr[d + 1], er[d + 1], a1);
                a2 = fmaf(xr[d + 2], er[d + 2], a2);
                a3 = fmaf(xr[d + 3], er[d + 3], a3);
            }
            float acc = (a0 + a1) + (a2 + a3);
            float dist = fmaf(-2.f, acc, xn + en[code]);
            if (dist < bd) { bd = dist; bk = code; }
        }
        #pragma unroll
        for (int off = 1; off < 64; off <<= 1) {
            float od = __shfl_xor(bd, off);
            int   ok = __shfl_xor(bk, off);
            if (od < bd || (od == bd && ok < bk)) { bd = od; bk = ok; }
        }
        if (bk != kg) {
            if (lane == 0) {
                probs[(size_t)row * K_CB + kg] = 0.f;
                probs[(size_t)row * K_CB + bk] = 1.f;
            }
            if (lane < 16)
                ((f32x4*)(zq + (size_t)row * D_DIM))[lane] =
                    ((const f32x4*)(emb + (size_t)bk * D_DIM))[lane];
        }
    }
}

extern "C" void kernel_launch(void* const* d_in, const int* in_sizes, int n_in,
                              void* d_out, int out_size, void* d_ws, size_t ws_size,
                              hipStream_t stream) {
    const float* x   = (const float*)d_in[0];   // [N, D] fp32
    const float* emb = (const float*)d_in[1];   // [K, D] fp32
    float* zq    = (float*)d_out;                              // [N, D]
    float* probs = (float*)d_out + (size_t)N_TOK * D_DIM;      // [N, K]

    char* ws = (char*)d_ws;
    float*  en      = (float*)(ws + WS_EN);
    ushort* es      = (ushort*)(ws + WS_ES);
    uint*   fixcnt  = (uint*)(ws + WS_CNT);
    uint*   fixlist = (uint*)(ws + WS_LIST);
    uint fixcap = (ws_size > WS_LIST + 4) ? (uint)((ws_size - WS_LIST) / 4) : 0u;

    prep_kernel<<<16, 256, 0, stream>>>(emb, en, es, fixcnt);
    vq_onehot<<<N_TOK / 64, 256, 0, stream>>>(x, emb, en, es, zq, probs, fixcnt, fixlist, fixcap);
    vq_fixup<<<256, 256, 0, stream>>>(x, emb, en, zq, probs, fixcnt, fixlist, fixcap);
}

// Round 8
// 661.232 us; speedup vs baseline: 1.2493x; 1.2493x over previous
//
#include <hip/hip_runtime.h>
#include <math.h>

#define N_TOK 131072
#define K_CB  1024
#define D_DIM 64
#define MARGIN 0.0625f

// ws layout: en[1024] f32 @0 ; es frag-major[131072] bf16 @4096 ; fixcnt @266240 ; fixlist @266248
#define WS_EN     0
#define WS_ES     4096
#define WS_CNT    266240
#define WS_LIST   266248

typedef short bf16x8 __attribute__((ext_vector_type(8)));
typedef float f32x4  __attribute__((ext_vector_type(4)));

__device__ __forceinline__ ushort f2bf(float f) {   // RNE fp32->bf16
    uint u = __float_as_uint(f);
    u += 0x7FFFu + ((u >> 16) & 1u);
    return (ushort)(u >> 16);
}
__device__ __forceinline__ float bf2f(ushort h) {
    return __uint_as_float(((uint)h) << 16);
}

// ---- kernel 1: prep. en[k] (R1-sequential rounding) + FRAG-MAJOR bf16 hi/lo split:
// es[(((cb*4+ks)*4+quad)*16+j)*8+e]  (cb=k>>4, j=k&15) so the main kernel's B-frag
// load for (cb,ks) is one contiguous 1KB wave load (lane = quad*16+j).
__global__ __launch_bounds__(256) void prep_kernel(
    const float* __restrict__ emb, float* __restrict__ en,
    ushort* __restrict__ es, uint* __restrict__ fixcnt)
{
    const int tid = threadIdx.x;
    const int pb  = blockIdx.x;
    const int c6  = tid & 63;
    const int q   = tid >> 6;
    const int code = pb * 64 + c6;
    if (pb == 0 && tid == 0) *fixcnt = 0;

    const int cb = code >> 4, jj = code & 15;
    const float* er = emb + (size_t)code * D_DIM;
    #pragma unroll
    for (int j = 0; j < 16; ++j) {
        int d = q * 16 + j;
        float f = er[d];
        ushort h = f2bf(f);
        ushort l = f2bf(f - bf2f(h));
        int ks = d >> 5, quad = (d >> 3) & 3, e = d & 7;
        es[(size_t)(((cb * 4 + ks)     * 4 + quad) * 16 + jj) * 8 + e] = h;
        es[(size_t)(((cb * 4 + ks + 2) * 4 + quad) * 16 + jj) * 8 + e] = l;
    }
    if (q == 0) {
        float s = 0.f;
        #pragma unroll
        for (int d = 0; d < D_DIM; ++d) s = fmaf(er[d], er[d], s);
        en[code] = s;
    }
}

// ---- kernel 2: wave-independent. Each wave: 32 rows' split-bf16 MFMA argmin
// (hi*hi + hi*lo + lo*hi), prefetched coalesced B-frags, shuffle top-2 merge,
// then zq gathers, then a PURE nt-store blast of 32 one-hot rows (no interleaved
// vmem loads -> full-rate write drain). block = 256 thr = 4 waves x 32 rows.
__global__ __launch_bounds__(256) void vq_onehot(
    const float* __restrict__ x, const float* __restrict__ emb,
    const float* __restrict__ en, const ushort* __restrict__ es,
    float* __restrict__ zq, float* __restrict__ probs,
    uint* __restrict__ fixcnt, uint* __restrict__ fixlist, uint fixcap)
{
    const int tid  = threadIdx.x;
    const int wave = tid >> 6, lane = tid & 63;
    const int quad = lane >> 4, l15 = lane & 15;
    const int waveRow = blockIdx.x * 128 + wave * 32;

    __shared__ int lds_bk[128];   // per-wave private 32-entry strips (no barrier needed)

    // A-frags per row-group g: [0]=hi d0..31, [1]=hi d32..63, [2]=lo d0..31, [3]=lo d32..63.
    // A layout (m120): A[m=lane&15][k=quad*8+j].
    bf16x8 af[2][4];
    #pragma unroll
    for (int g = 0; g < 2; ++g) {
        const float* xr = x + (size_t)(waveRow + g * 16 + l15) * D_DIM + quad * 8;
        f32x4 p0 = *(const f32x4*)(xr);
        f32x4 p1 = *(const f32x4*)(xr + 4);
        f32x4 p2 = *(const f32x4*)(xr + 32);
        f32x4 p3 = *(const f32x4*)(xr + 36);
        float v0[8], v1[8];
        #pragma unroll
        for (int j = 0; j < 4; ++j) { v0[j] = p0[j]; v0[4 + j] = p1[j]; v1[j] = p2[j]; v1[4 + j] = p3[j]; }
        #pragma unroll
        for (int j = 0; j < 8; ++j) {
            ushort h0 = f2bf(v0[j]);
            af[g][0][j] = (short)h0;
            af[g][2][j] = (short)f2bf(v0[j] - bf2f(h0));
            ushort h1 = f2bf(v1[j]);
            af[g][1][j] = (short)h1;
            af[g][3][j] = (short)f2bf(v1[j] - bf2f(h1));
        }
    }

    float b1[8], b2[8]; int k1[8];
    #pragma unroll
    for (int s = 0; s < 8; ++s) { b1[s] = INFINITY; b2[s] = INFINITY; k1[s] = 0; }

    const bf16x8* __restrict__ esv = (const bf16x8*)es;   // frag-major
    const int fidx = quad * 16 + l15;                     // == lane: contiguous 1KB per inst

    // prefetch chunk 0
    bf16x8 bc[4]; float enc;
    #pragma unroll
    for (int ks = 0; ks < 4; ++ks) bc[ks] = esv[ks * 64 + fidx];
    enc = en[l15];

    #pragma unroll 2
    for (int cb = 0; cb < 64; ++cb) {
        // prefetch next chunk (wraps at the end; harmless re-read)
        const int nb = (cb + 1) & 63;
        bf16x8 bn[4]; float enn;
        #pragma unroll
        for (int ks = 0; ks < 4; ++ks) bn[ks] = esv[(size_t)nb * 256 + ks * 64 + fidx];
        enn = en[nb * 16 + l15];

        f32x4 acc0 = {0.f, 0.f, 0.f, 0.f};
        f32x4 acc1 = {0.f, 0.f, 0.f, 0.f};
        // dot = xh*eh + xh*el + xl*eh  (xl*el ~1e-4, absorbed by MARGIN)
        acc0 = __builtin_amdgcn_mfma_f32_16x16x32_bf16(af[0][0], bc[0], acc0, 0, 0, 0);
        acc0 = __builtin_amdgcn_mfma_f32_16x16x32_bf16(af[0][1], bc[1], acc0, 0, 0, 0);
        acc0 = __builtin_amdgcn_mfma_f32_16x16x32_bf16(af[0][0], bc[2], acc0, 0, 0, 0);
        acc0 = __builtin_amdgcn_mfma_f32_16x16x32_bf16(af[0][1], bc[3], acc0, 0, 0, 0);
        acc0 = __builtin_amdgcn_mfma_f32_16x16x32_bf16(af[0][2], bc[0], acc0, 0, 0, 0);
        acc0 = __builtin_amdgcn_mfma_f32_16x16x32_bf16(af[0][3], bc[1], acc0, 0, 0, 0);
        acc1 = __builtin_amdgcn_mfma_f32_16x16x32_bf16(af[1][0], bc[0], acc1, 0, 0, 0);
        acc1 = __builtin_amdgcn_mfma_f32_16x16x32_bf16(af[1][1], bc[1], acc1, 0, 0, 0);
        acc1 = __builtin_amdgcn_mfma_f32_16x16x32_bf16(af[1][0], bc[2], acc1, 0, 0, 0);
        acc1 = __builtin_amdgcn_mfma_f32_16x16x32_bf16(af[1][1], bc[3], acc1, 0, 0, 0);
        acc1 = __builtin_amdgcn_mfma_f32_16x16x32_bf16(af[1][2], bc[0], acc1, 0, 0, 0);
        acc1 = __builtin_amdgcn_mfma_f32_16x16x32_bf16(af[1][3], bc[1], acc1, 0, 0, 0);

        const int code = cb * 16 + l15;
        // C layout (m89): col = lane&15 (this lane's code), row = quad*4 + r.
        #pragma unroll
        for (int r = 0; r < 4; ++r) {
            {
                float d = fmaf(-2.f, acc0[r], enc);
                bool lt = d < b1[r];
                b2[r] = lt ? b1[r] : fminf(b2[r], d);
                k1[r] = lt ? code : k1[r];
                b1[r] = lt ? d : b1[r];
            }
            {
                int s = 4 + r;
                float d = fmaf(-2.f, acc1[r], enc);
                bool lt = d < b1[s];
                b2[s] = lt ? b1[s] : fminf(b2[s], d);
                k1[s] = lt ? code : k1[s];
                b1[s] = lt ? d : b1[s];
            }
        }

        #pragma unroll
        for (int ks = 0; ks < 4; ++ks) bc[ks] = bn[ks];
        enc = enn;
    }

    // butterfly top-2 merge across the 16 lanes holding one row's columns
    #pragma unroll
    for (int s = 0; s < 8; ++s) {
        #pragma unroll
        for (int off = 1; off < 16; off <<= 1) {
            float ob1 = __shfl_xor(b1[s], off);
            int   ok1 = __shfl_xor(k1[s], off);
            float ob2 = __shfl_xor(b2[s], off);
            bool better = (ob1 < b1[s]) || (ob1 == b1[s] && ok1 < k1[s]);
            float loser = better ? b1[s] : ob1;
            b1[s] = better ? ob1 : b1[s];
            k1[s] = better ? ok1 : k1[s];
            b2[s] = fminf(fminf(b2[s], ob2), loser);
        }
    }

    // leaders publish bk to wave-private LDS strip + flag uncertain rows
    if (l15 == 0) {
        #pragma unroll
        for (int s = 0; s < 8; ++s) {
            int lrow = wave * 32 + (s >> 2) * 16 + quad * 4 + (s & 3);
            lds_bk[lrow] = k1[s];
            if (b2[s] - b1[s] <= MARGIN) {
                uint idx = atomicAdd(fixcnt, 1u);
                if (idx < fixcap)
                    fixlist[idx] = (uint)(blockIdx.x * 128 + lrow) | ((uint)k1[s] << 17);
            }
        }
    }

    // zq: 8 groups of 4 rows; quad handles row mb*4+quad, l15 = col (16B each)
    #pragma unroll
    for (int mb = 0; mb < 8; ++mb) {
        int bk = lds_bk[wave * 32 + mb * 4 + quad];
        f32x4 v = ((const f32x4*)(emb + (size_t)bk * D_DIM))[l15];
        ((f32x4*)(zq + (size_t)(waveRow + mb * 4 + quad) * D_DIM))[l15] = v;
    }

    // one-hot blast: 32 rows x 4KB, pure nt-store stream (bk via LDS broadcast,
    // no vmem loads between stores -> in-order vmcnt never stalls the stream)
    for (int m = 0; m < 32; ++m) {
        int bk = lds_bk[wave * 32 + m];           // uniform address -> LDS broadcast
        float* prow = probs + (size_t)(waveRow + m) * K_CB;
        #pragma unroll
        for (int s = 0; s < 4; ++s) {
            int c = s * 256 + lane * 4;
            f32x4 v;
            v[0] = (c     == bk) ? 1.f : 0.f;
            v[1] = (c + 1 == bk) ? 1.f : 0.f;
            v[2] = (c + 2 == bk) ? 1.f : 0.f;
            v[3] = (c + 3 == bk) ? 1.f : 0.f;
            __builtin_nontemporal_store(v, (f32x4*)(prow + c));
        }
    }
}

// ---- kernel 3: exact fp32 re-argmin (bit-identical to the R1/R2 formula) for flagged rows ----
__global__ __launch_bounds__(256) void vq_fixup(
    const float* __restrict__ x, const float* __restrict__ emb,
    const float* __restrict__ en,
    float* __restrict__ zq, float* __restrict__ probs,
    const uint* __restrict__ fixcnt, const uint* __restrict__ fixlist, uint fixcap)
{
    const int lane = threadIdx.x & 63;
    const uint gwave = (uint)((blockIdx.x * 256 + threadIdx.x) >> 6);
    uint cnt = *fixcnt;
    if (cnt > fixcap) cnt = fixcap;

    for (uint e = gwave; e < cnt; e += 1024u) {
        uint w = fixlist[e];
        int row = (int)(w & 0x1FFFFu);
        int kg  = (int)(w >> 17);
        const float* xr = x + (size_t)row * D_DIM;
        float xn = 0.f;
        #pragma unroll
        for (int d = 0; d < D_DIM; ++d) xn = fmaf(xr[d], xr[d], xn);

        float bd = INFINITY; int bk = 0;
        for (int t = 0; t < 16; ++t) {
            int code = t * 64 + lane;                 // ascending per lane
            const float* er = emb + (size_t)code * D_DIM;
            float a0 = 0.f, a1 = 0.f, a2 = 0.f, a3 = 0.f;
            #pragma unroll
            for (int d = 0; d < D_DIM; d += 4) {
                a0 = fmaf(xr[d + 0], er[d + 0], a0);
                a1 = fmaf(xr[d + 1], er[d + 1], a1);
                a2 = fmaf(xr[d + 2], er[d + 2], a2);
                a3 = fmaf(xr[d + 3], er[d + 3], a3);
            }
            float acc = (a0 + a1) + (a2 + a3);
            float dist = fmaf(-2.f, acc, xn + en[code]);
            if (dist < bd) { bd = dist; bk = code; }
        }
        #pragma unroll
        for (int off = 1; off < 64; off <<= 1) {
            float od = __shfl_xor(bd, off);
            int   ok = __shfl_xor(bk, off);
            if (od < bd || (od == bd && ok < bk)) { bd = od; bk = ok; }
        }
        if (bk != kg) {
            if (lane == 0) {
                probs[(size_t)row * K_CB + kg] = 0.f;
                probs[(size_t)row * K_CB + bk] = 1.f;
            }
            if (lane < 16)
                ((f32x4*)(zq + (size_t)row * D_DIM))[lane] =
                    ((const f32x4*)(emb + (size_t)bk * D_DIM))[lane];
        }
    }
}

extern "C" void kernel_launch(void* const* d_in, const int* in_sizes, int n_in,
                              void* d_out, int out_size, void* d_ws, size_t ws_size,
                              hipStream_t stream) {
    const float* x   = (const float*)d_in[0];   // [N, D] fp32
    const float* emb = (const float*)d_in[1];   // [K, D] fp32
    float* zq    = (float*)d_out;                              // [N, D]
    float* probs = (float*)d_out + (size_t)N_TOK * D_DIM;      // [N, K]

    char* ws = (char*)d_ws;
    float*  en      = (float*)(ws + WS_EN);
    ushort* es      = (ushort*)(ws + WS_ES);
    uint*   fixcnt  = (uint*)(ws + WS_CNT);
    uint*   fixlist = (uint*)(ws + WS_LIST);
    uint fixcap = (ws_size > WS_LIST + 4) ? (uint)((ws_size - WS_LIST) / 4) : 0u;

    prep_kernel<<<16, 256, 0, stream>>>(emb, en, es, fixcnt);
    vq_onehot<<<N_TOK / 128, 256, 0, stream>>>(x, emb, en, es, zq, probs, fixcnt, fixlist, fixcap);
    vq_fixup<<<256, 256, 0, stream>>>(x, emb, en, zq, probs, fixcnt, fixlist, fixcap);
}